// Round 7
// baseline (126.898 us; speedup 1.0000x reference)
//
#include <hip/hip_runtime.h>

// Problem constants (fixed by the reference):
//   input:       [TP=8, NTOK=2048, HIDDEN=8192] f32
//   residual:    [NTOK, HIDDEN] f32
//   norm_weight: [HIDDEN] f32
// Outputs (concatenated in d_out): output [NTOK,HIDDEN], residual_out [NTOK,HIDDEN]
//
// R7 = R6 with the store burst moved AFTER the barrier. R6 issued the
// residual_out stores before __syncthreads, whose implicit
// `s_waitcnt vmcnt(0)` forced every block to wait for store COMMIT before
// crossing. Loads are all consumed by reduce time, so with no pre-barrier
// stores the barrier drain is ~free. Post-barrier, one fused loop computes
// the normalized output and issues both NT stores; the kernel retires with
// stores in flight.
constexpr int TP     = 8;
constexpr int HIDDEN = 8192;
constexpr int BLOCK  = 256;
constexpr int VPT    = HIDDEN / (BLOCK * 4);  // 8 float4 per thread
constexpr float EPS  = 1e-6f;

typedef float f32x4 __attribute__((ext_vector_type(4)));

__global__ __launch_bounds__(BLOCK) void ar_residual_rmsnorm_kernel(
    const float* __restrict__ in,         // [TP, ntok, HIDDEN]
    const float* __restrict__ resid,      // [ntok, HIDDEN]
    const float* __restrict__ w,          // [HIDDEN]
    float* __restrict__ out,              // [ntok, HIDDEN]
    float* __restrict__ resid_out,        // [ntok, HIDDEN]
    int ntok)
{
    const int row = blockIdx.x;
    const int tid = threadIdx.x;
    const size_t row_off     = (size_t)row * HIDDEN;
    const size_t rank_stride = (size_t)ntok * HIDDEN;

    // Pass 1: PURE READS. Allreduce-sum + residual add into registers,
    // accumulate sum of squares. No stores before the barrier.
    f32x4 v[VPT];
    f32x4 ssv = {0.f, 0.f, 0.f, 0.f};
    #pragma unroll
    for (int p = 0; p < VPT; ++p) {
        const int col = (tid + p * BLOCK) * 4;  // float index, 16B aligned
        const float* base = in + row_off + col;
        f32x4 x0 = __builtin_nontemporal_load((const f32x4*)(base + 0 * rank_stride));
        f32x4 x1 = __builtin_nontemporal_load((const f32x4*)(base + 1 * rank_stride));
        f32x4 x2 = __builtin_nontemporal_load((const f32x4*)(base + 2 * rank_stride));
        f32x4 x3 = __builtin_nontemporal_load((const f32x4*)(base + 3 * rank_stride));
        f32x4 x4 = __builtin_nontemporal_load((const f32x4*)(base + 4 * rank_stride));
        f32x4 x5 = __builtin_nontemporal_load((const f32x4*)(base + 5 * rank_stride));
        f32x4 x6 = __builtin_nontemporal_load((const f32x4*)(base + 6 * rank_stride));
        f32x4 x7 = __builtin_nontemporal_load((const f32x4*)(base + 7 * rank_stride));
        f32x4 rv = __builtin_nontemporal_load((const f32x4*)(resid + row_off + col));
        f32x4 s01 = x0 + x1, s23 = x2 + x3, s45 = x4 + x5, s67 = x6 + x7;
        f32x4 acc = (s01 + s23) + (s45 + s67) + rv;
        v[p] = acc;
        ssv += acc * acc;
    }

    float ss = ssv.x + ssv.y + ssv.z + ssv.w;

    // Block reduction of ss: butterfly within each 64-lane wave, then LDS.
    // All loads are consumed above, no stores issued yet -> the barrier's
    // implicit vmcnt(0) drain is essentially free.
    #pragma unroll
    for (int o = 32; o > 0; o >>= 1) ss += __shfl_down(ss, o, 64);
    __shared__ float s_ss[BLOCK / 64];
    const int wid = tid >> 6;
    if ((tid & 63) == 0) s_ss[wid] = ss;
    __syncthreads();
    float tot = 0.f;
    #pragma unroll
    for (int i = 0; i < BLOCK / 64; ++i) tot += s_ss[i];

    const float inv = rsqrtf(tot * (1.0f / HIDDEN) + EPS);

    // Pass 2 (fused stores): residual_out and normalized output from
    // registers. Kernel retires with stores in flight.
    #pragma unroll
    for (int p = 0; p < VPT; ++p) {
        const int col = (tid + p * BLOCK) * 4;
        __builtin_nontemporal_store(v[p], (f32x4*)(resid_out + row_off + col));
        f32x4 wv = *(const f32x4*)(w + col);   // reused by all blocks -> cached
        f32x4 o4 = v[p] * inv * wv;
        __builtin_nontemporal_store(o4, (f32x4*)(out + row_off + col));
    }
}

extern "C" void kernel_launch(void* const* d_in, const int* in_sizes, int n_in,
                              void* d_out, int out_size, void* d_ws, size_t ws_size,
                              hipStream_t stream) {
    const float* in    = (const float*)d_in[0];
    const float* resid = (const float*)d_in[1];
    const float* w     = (const float*)d_in[2];

    const int hidden = in_sizes[2];          // 8192
    const int ntok   = in_sizes[1] / hidden; // 2048

    float* out       = (float*)d_out;                         // [ntok, hidden]
    float* resid_out = (float*)d_out + (size_t)ntok * hidden; // [ntok, hidden]

    ar_residual_rmsnorm_kernel<<<ntok, BLOCK, 0, stream>>>(
        in, resid, w, out, resid_out, ntok);
}